// Round 1
// baseline (410.678 us; speedup 1.0000x reference)
//
#include <hip/hip_runtime.h>

// QuantumConvLayer: probs of RX(theta)⊗RY(theta)+CNOT circuit, theta = in[:,0].
// probs = [c2*c2, c2*s2, s2*s2, s2*c2], c2=cos^2(theta/2)=(1+cos theta)/2.
// Memory-bound: 256 MB in + 256 MB out -> ~81 us floor at 6.3 TB/s.

__global__ __launch_bounds__(256) void qprobs_kernel(const float4* __restrict__ in,
                                                     float4* __restrict__ out,
                                                     int n_rows) {
    int i = blockIdx.x * 256 + threadIdx.x;
    if (i >= n_rows) return;
    // 16B coalesced load; theta lives in .x, rest of the row is unused input.
    float theta = in[i].x;
    float c = cosf(theta);
    float c2 = 0.5f * (1.0f + c);   // cos^2(theta/2)
    float s2 = 0.5f * (1.0f - c);   // sin^2(theta/2)
    float4 p;
    p.x = c2 * c2;
    p.y = c2 * s2;
    p.z = s2 * s2;
    p.w = s2 * c2;
    out[i] = p;  // 16B coalesced store
}

extern "C" void kernel_launch(void* const* d_in, const int* in_sizes, int n_in,
                              void* d_out, int out_size, void* d_ws, size_t ws_size,
                              hipStream_t stream) {
    const float4* in = (const float4*)d_in[0];
    float4* out = (float4*)d_out;
    int n_rows = in_sizes[0] / 4;          // 16777216
    int blocks = (n_rows + 255) / 256;     // 65536
    qprobs_kernel<<<blocks, 256, 0, stream>>>(in, out, n_rows);
}

// Round 3
// 410.508 us; speedup vs baseline: 1.0004x; 1.0004x over previous
//
#include <hip/hip_runtime.h>

// QuantumConvLayer: probs of RX(theta)⊗RY(theta)+CNOT circuit, theta = in[:,0].
// probs = [c2*c2, c2*s2, s2*s2, s2*c2], c2=cos^2(theta/2)=(1+cos theta)/2.
// Memory-bound: 256 MB in (full lines touched; only col 0 used) + 256 MB out
// -> ~81 us floor at 6.3 TB/s achievable.
//
// Shape: grid-stride, 4 rows/thread, 16384 blocks x 256. Load only theta
// (4 B/lane, same HBM lines as a full-row load), nontemporal in/out (no reuse,
// both streams >> 32 MB L2). Native clang vector type for the nontemporal
// store (HIP float4 is a class -> builtin rejects it).

typedef float v4f __attribute__((ext_vector_type(4)));

#define ROWS_PER_THREAD 4

__global__ __launch_bounds__(256) void qprobs_kernel(const float* __restrict__ in,
                                                     v4f* __restrict__ out,
                                                     int n_rows) {
    int stride = gridDim.x * 256;
    int i = blockIdx.x * 256 + threadIdx.x;
#pragma unroll
    for (int r = 0; r < ROWS_PER_THREAD; ++r, i += stride) {
        if (i < n_rows) {
            // theta = row i, column 0; rows are 4 floats apart.
            float theta = __builtin_nontemporal_load(in + 4 * (size_t)i);
            float c = __cosf(theta);
            float c2 = 0.5f * (1.0f + c);   // cos^2(theta/2)
            float s2 = 0.5f * (1.0f - c);   // sin^2(theta/2)
            v4f p;
            p.x = c2 * c2;
            p.y = c2 * s2;
            p.z = s2 * s2;
            p.w = s2 * c2;
            __builtin_nontemporal_store(p, out + i);
        }
    }
}

extern "C" void kernel_launch(void* const* d_in, const int* in_sizes, int n_in,
                              void* d_out, int out_size, void* d_ws, size_t ws_size,
                              hipStream_t stream) {
    const float* in = (const float*)d_in[0];
    v4f* out = (v4f*)d_out;
    int n_rows = in_sizes[0] / 4;                                   // 16777216
    int threads_total = (n_rows + ROWS_PER_THREAD - 1) / ROWS_PER_THREAD;
    int blocks = (threads_total + 255) / 256;                       // 16384
    qprobs_kernel<<<blocks, 256, 0, stream>>>(in, out, n_rows);
}